// Round 15
// baseline (310.779 us; speedup 1.0000x reference)
//
#include <hip/hip_runtime.h>

// GroupedQueryAttention on MI355X (gfx950), round 16.
// B=2, S=2048, E=2048, H=32, KVH=8, G=4, D=64.
// Round-15 post-mortem: GEMM launch_bounds (256,3) REGRESSED (299.7->306.9;
// attn control unchanged) -- the 170-VGPR cap / 96KB LDS residency costs more
// than the 3rd block buys. REVERTED to verified round-14 config: (256,2), BK=64.
// This round's single variable: bijective XCD swizzle on the GEMM grid
// (nwg 768 / 512, both %8==0). nid=(L&7)*(nwg/8)+(L>>3): each XCD owns 3
// consecutive n-tiles x all m-tiles -> B working set 1.5MB, L2-resident
// (was: all panel reuse via L3; A 16MB + WT 12.6MB both L3-fit, so the GEMM
// is L2-locality-bound, T1's exact regime, m192 +10%). Zero reg/LDS impact.
// attn kernel byte-identical to round 10 (verified 77-78.5us plateau).

typedef __attribute__((ext_vector_type(8)))  short     s16x8;
typedef __attribute__((ext_vector_type(8)))  _Float16  h8;
typedef __attribute__((ext_vector_type(2)))  __fp16    fp16x2;
typedef __attribute__((ext_vector_type(4)))  float     f32x4;
typedef __attribute__((ext_vector_type(16))) float     f32x16;

#define DEVI static __device__ __forceinline__

#if __has_builtin(__builtin_amdgcn_exp2f)
#define EXP2F __builtin_amdgcn_exp2f
#else
#define EXP2F exp2f
#endif

DEVI short f2h(float f){ _Float16 h = (_Float16)f; return __builtin_bit_cast(short, h); }
DEVI unsigned pkh(float a, float b){            // two f32 -> packed f16 (RTZ), 1 instr
  fp16x2 t = __builtin_amdgcn_cvt_pkrtz(a, b);
  return __builtin_bit_cast(unsigned, t);
}

typedef __attribute__((address_space(3))) unsigned       lds_u32;
typedef __attribute__((address_space(1))) const unsigned gbl_u32;
DEVI void glds16(const short* g, short* l){
  __builtin_amdgcn_global_load_lds((gbl_u32*)g, (lds_u32*)l, 16, 0, 0);
}

// ---------------- cast fp32 -> f16 ----------------
__global__ void cast_kernel(const float* __restrict__ in, short* __restrict__ out, int n){
  int i = (blockIdx.x * 256 + threadIdx.x) * 8;
  if(i >= n) return;
  float4 a = *(const float4*)(in + i);
  float4 b = *(const float4*)(in + i + 4);
  s16x8 v;
  v[0]=f2h(a.x); v[1]=f2h(a.y); v[2]=f2h(a.z); v[3]=f2h(a.w);
  v[4]=f2h(b.x); v[5]=f2h(b.y); v[6]=f2h(b.z); v[7]=f2h(b.w);
  *(s16x8*)(out + i) = v;
}

// ---------------- merged weight transposes (fp32 -> f16) + bias concat -------
// grid (32, 81): gy 0..31 Wq, 32..39 Wk, 40..47 Wv, 48..79 Wo, 80 bias concat
__global__ void prep_kernel(const float* __restrict__ Wq, const float* __restrict__ Wk,
                            const float* __restrict__ Wv, const float* __restrict__ Wo,
                            const float* __restrict__ bq, const float* __restrict__ bk,
                            const float* __restrict__ bv,
                            short* __restrict__ WT, short* __restrict__ WoT,
                            float* __restrict__ bqkv){
  __shared__ __align__(16) short tile[64*72];
  const int gy = blockIdx.y;
  const int t = threadIdx.x;
  if(gy >= 80){
    int i = blockIdx.x * 256 + t;
    if(i < 3072) bqkv[i] = (i < 2048) ? bq[i] : (i < 2560 ? bk[i-2048] : bv[i-2560]);
    return;
  }
  const float* src; short* dst; int ldin, by;
  if(gy < 32)      { src = Wq; dst = WT;             ldin = 2048; by = gy;    }
  else if(gy < 40) { src = Wk; dst = WT + 2048*2048; ldin =  512; by = gy-32; }
  else if(gy < 48) { src = Wv; dst = WT + 2560*2048; ldin =  512; by = gy-40; }
  else             { src = Wo; dst = WoT;            ldin = 2048; by = gy-48; }
  const int tr = blockIdx.x * 64;
  const int tc = by * 64;
  for(int c = t; c < 512; c += 256){
    int r = c >> 3, g = c & 7;
    const float* p = src + (size_t)(tr + r) * ldin + tc + g*8;
    s16x8 v;
    #pragma unroll
    for(int e = 0; e < 8; e++) v[e] = f2h(p[e]);
    *(s16x8*)&tile[r*72 + g*8] = v;
  }
  __syncthreads();
  for(int c = t; c < 512; c += 256){
    int r = c >> 3, g = c & 7;
    s16x8 v;
    #pragma unroll
    for(int e = 0; e < 8; e++) v[e] = tile[(g*8+e)*72 + r];
    *(s16x8*)(dst + (size_t)(tc + r) * 2048 + tr + g*8) = v;
  }
}

// ---------------- GEMM (f16): C[M][N] = A[M][K] * BT[N][K]^T + bias[N] -------
// BK=64 (two 32-wide sub-tiles per barrier pair, af/bfr regs reused),
// launch_bounds (256,2) [round-14 verified config]. XCD-swizzled block ids:
// each XCD owns a contiguous nid range -> few B-panels, L2-resident.
template<bool OUT_F32>
__global__ __launch_bounds__(256, 2)
void gemm_bt_kernel(const short* __restrict__ A, const short* __restrict__ BT,
                    const float* __restrict__ bias, void* __restrict__ C,
                    int M, int N, int K, int scale_cols, float qscale){
  __shared__ __align__(16) short As[2][128*32];
  __shared__ __align__(16) short Bs[2][128*32];
  // bijective XCD swizzle (nwg % 8 == 0 for both grids: 768, 512)
  const int nwg = gridDim.x * gridDim.y;
  const int L   = blockIdx.y * gridDim.x + blockIdx.x;
  const int nid = (L & 7) * (nwg >> 3) + (L >> 3);
  const int m0 = (nid & 31) * 128;           // gridDim.x == 32
  const int n0 = (nid >> 5) * 128;
  const int tid = threadIdx.x;
  const int wave = tid >> 6, lane = tid & 63;
  const int l16 = lane & 15, quad = lane >> 4;
  const int wm = (wave >> 1) * 64, wn = (wave & 1) * 64;

  const short* gA = A  + (size_t)(m0 + wave*32 + (lane>>2))*K + (lane&3)*8;
  const short* gB = BT + (size_t)(n0 + wave*32 + (lane>>2))*K + (lane&3)*8;
  short* lA0 = As[0] + wave*1024;
  short* lA1 = As[1] + wave*1024;
  short* lB0 = Bs[0] + wave*1024;
  short* lB1 = Bs[1] + wave*1024;

  f32x4 acc[4][4];
  #pragma unroll
  for(int i=0;i<4;i++)
    #pragma unroll
    for(int j=0;j<4;j++) acc[i][j] = (f32x4)(0.0f);

  for(int k0 = 0; k0 < K; k0 += 64){
    glds16(gA + k0,                     lA0);
    glds16(gA + 16*(size_t)K + k0,      lA0 + 512);
    glds16(gA + k0 + 32,                lA1);
    glds16(gA + 16*(size_t)K + k0 + 32, lA1 + 512);
    glds16(gB + k0,                     lB0);
    glds16(gB + 16*(size_t)K + k0,      lB0 + 512);
    glds16(gB + k0 + 32,                lB1);
    glds16(gB + 16*(size_t)K + k0 + 32, lB1 + 512);
    __syncthreads();
    h8 af[4], bfr[4];
    #pragma unroll
    for(int i=0;i<4;i++){
      af[i]  = *(const h8*)&As[0][(wm + i*16 + l16)*32 + quad*8];
      bfr[i] = *(const h8*)&Bs[0][(wn + i*16 + l16)*32 + quad*8];
    }
    #pragma unroll
    for(int i=0;i<4;i++)
      #pragma unroll
      for(int j=0;j<4;j++)
        acc[i][j] = __builtin_amdgcn_mfma_f32_16x16x32_f16(af[i], bfr[j], acc[i][j], 0, 0, 0);
    #pragma unroll
    for(int i=0;i<4;i++){
      af[i]  = *(const h8*)&As[1][(wm + i*16 + l16)*32 + quad*8];
      bfr[i] = *(const h8*)&Bs[1][(wn + i*16 + l16)*32 + quad*8];
    }
    #pragma unroll
    for(int i=0;i<4;i++)
      #pragma unroll
      for(int j=0;j<4;j++)
        acc[i][j] = __builtin_amdgcn_mfma_f32_16x16x32_f16(af[i], bfr[j], acc[i][j], 0, 0, 0);
    __syncthreads();
  }

  #pragma unroll
  for(int j=0;j<4;j++){
    int col = n0 + wn + j*16 + l16;
    float bb = bias[col];
    float sc = (col < scale_cols) ? qscale : 1.0f;
    #pragma unroll
    for(int i=0;i<4;i++){
      #pragma unroll
      for(int r=0;r<4;r++){
        size_t row = (size_t)(m0 + wm + i*16 + quad*4 + r);
        float v = (acc[i][j][r] + bb) * sc;
        if(OUT_F32) ((float*)C)[row*(size_t)N + col] = v;
        else        ((short*)C)[row*(size_t)N + col] = f2h(v);
      }
    }
  }
}

// ---------------- K/V fragment pre-pack ----------------
// grid (32 tiles, 8 kvh, 2 b), 256 thr. Reads the K and V column slices of
// QKV for one 64-key tile into LDS, emits MFMA A-fragment-ordered chunks:
//   Kf chunk (t,kb,ks2,l):  K[t*64+kb*32+(l&31)][ks2*16+(l>>5)*8 .. +8]
//   Vf chunk (t,kb,ksp,mb,l): keys k0..k0+3, k0+8..k0+11 (k0=kb*32+ksp*16+(l>>5)*4)
//                             at d = mb*32+(l&31)   (the PV kappa order)
// Chunk index within a tile == the lane that will read it -> attn loads are
// lane-contiguous global_load_dwordx4 and the stream is fully sequential.
__global__ void fragpack_kernel(const short* __restrict__ QKV,
                                short* __restrict__ Kf, short* __restrict__ Vf){
  __shared__ __align__(16) short kt[64*72];
  __shared__ __align__(16) short vt[64*72];
  const int t = blockIdx.x, kvh = blockIdx.y, b = blockIdx.z;
  const int tid = threadIdx.x;
  const size_t rowbase = (size_t)(b*2048 + t*64);
  for(int c = tid; c < 512; c += 256){
    int r = c >> 3, g = c & 7;
    const short* src = QKV + (rowbase + r)*3072 + kvh*64 + g*8;
    *(s16x8*)&kt[r*72 + g*8] = *(const s16x8*)(src + 2048);
    *(s16x8*)&vt[r*72 + g*8] = *(const s16x8*)(src + 2560);
  }
  __syncthreads();
  const size_t obase = ((size_t)(b*8 + kvh)*32 + t) * 4096;
  for(int ch = tid; ch < 512; ch += 256){
    int kb = ch >> 8, l = ch & 63;
    int c = l & 31, h = l >> 5;
    // K chunk: ch = kb*256 + ks2*64 + l
    int ks2 = (ch >> 6) & 3;
    *(s16x8*)(Kf + obase + (size_t)ch*8) =
        *(const s16x8*)&kt[(kb*32 + c)*72 + ks2*16 + h*8];
    // V chunk: ch = kb*256 + ksp*128 + mb*64 + l
    int ksp = (ch >> 7) & 1, mb = (ch >> 6) & 1;
    int k0 = kb*32 + ksp*16 + h*4;
    int d  = mb*32 + c;
    s16x8 v;
    #pragma unroll
    for(int j = 0; j < 4; j++){
      v[j]   = vt[(k0 + j)*72 + d];
      v[4+j] = vt[(k0 + 8 + j)*72 + d];
    }
    *(s16x8*)(Vf + obase + (size_t)ch*8) = v;
  }
}

// ---------------- flash attention: LDS-free, global frag streams ----------
// EXACT round-10 kernel (verified 77-78.5us, 120 VGPR, no scratch).
// 512 blocks (XCD-swizzled) x 4 waves (= 4 heads of one KV group, 64-row
// q-tile). Per half-tile (32 keys): 8 coalesced b128 frag loads (K 4, V 4),
// S^T = K*Q^T (32x32x16 f16), max-free exp2 softmax packed in-register as the
// PV B-operand, O^T accumulated in f32x16. Register double buffer: frags for
// half-tile it+1 are issued before computing it. No LDS, no barriers.
__global__ __launch_bounds__(256, 2)
void attn_kernel(const short* __restrict__ Qg, const short* __restrict__ Kf,
                 const short* __restrict__ Vf, short* __restrict__ Og, int ldq){
  const int L = blockIdx.x;
  const int nid = (L & 7)*64 + (L >> 3);   // XCD swizzle: XCD x owns nid [x*64, x*64+64)
  const int qt  = nid & 31;                // 64-row q tile
  const int grp = nid >> 5;                // = b*8 + kvh  (2 groups per XCD -> 1 MB in L2)
  const int kvh = grp & 7, b = grp >> 3;
  const int tid = threadIdx.x;
  const int wave = tid >> 6, lane = tid & 63;
  const int c = lane & 31, h = lane >> 5;
  const int head = kvh*4 + wave;
  const int q0 = qt * 64;

  // Q B-fragments (pre-scaled by 0.125*log2e in GEMM epilogue)
  h8 qreg[4][2];
  #pragma unroll
  for(int ks2=0; ks2<4; ks2++)
    #pragma unroll
    for(int qg=0; qg<2; qg++)
      qreg[ks2][qg] = *(const h8*)(Qg + (size_t)(b*2048 + q0 + qg*32 + c)*ldq
                                      + head*64 + ks2*16 + h*8);

  float lsum[2] = {0.0f, 0.0f};
  f32x16 oacc[2][2];               // [qg][mb]  O^T block: rows d, cols q
  #pragma unroll
  for(int qg=0; qg<2; qg++)
    #pragma unroll
    for(int mb=0; mb<2; mb++) oacc[qg][mb] = (f32x16)(0.0f);

  const short* kp = Kf + (size_t)grp * 131072 + lane*8;
  const short* vp = Vf + (size_t)grp * 131072 + lane*8;

  h8 kA[4], vA[4], kB[4], vB[4];

  auto loadf = [&](size_t it, h8* K, h8* V){
    const short* kq = kp + it*2048;
    const short* vq = vp + it*2048;
    #pragma unroll
    for(int i=0;i<4;i++){
      K[i] = *(const h8*)(kq + i*512);
      V[i] = *(const h8*)(vq + i*512);
    }
  };

  auto compute = [&](const h8* K, const h8* V){
    f32x16 st[2];
    st[0] = (f32x16)(0.0f); st[1] = (f32x16)(0.0f);
    #pragma unroll
    for(int ks2=0; ks2<4; ks2++){
      st[0] = __builtin_amdgcn_mfma_f32_32x32x16_f16(K[ks2], qreg[ks2][0], st[0], 0, 0, 0);
      st[1] = __builtin_amdgcn_mfma_f32_32x32x16_f16(K[ks2], qreg[ks2][1], st[1], 0, 0, 0);
    }
    union H8U { h8 v; unsigned u[4]; };
    H8U pk[2][2];                  // [qg][ksp]
    #pragma unroll
    for(int qg=0; qg<2; qg++){
      float sacc = 0.0f;
      #pragma unroll
      for(int j=0; j<4; j++){
        float pa = EXP2F(st[qg][2*j]);
        float pb = EXP2F(st[qg][2*j+1]);
        sacc += pa + pb;
        pk[qg][0].u[j] = pkh(pa, pb);
      }
      #pragma unroll
      for(int j=0; j<4; j++){
        float pa = EXP2F(st[qg][8+2*j]);
        float pb = EXP2F(st[qg][8+2*j+1]);
        sacc += pa + pb;
        pk[qg][1].u[j] = pkh(pa, pb);
      }
      lsum[qg] += sacc;
    }
    #pragma unroll
    for(int ksp=0; ksp<2; ksp++){
      #pragma unroll
      for(int mb=0; mb<2; mb++){
        oacc[0][mb] = __builtin_amdgcn_mfma_f32_32x32x16_f16(V[ksp*2+mb], pk[0][ksp].v, oacc[0][mb], 0, 0, 0);
        oacc[1][mb] = __builtin_amdgcn_mfma_f32_32x32x16_f16(V[ksp*2+mb], pk[1][ksp].v, oacc[1][mb], 0, 0, 0);
      }
    }
  };

  loadf(0, kA, vA);
  #pragma unroll 1
  for(int it = 0; it < 64; it += 2){
    loadf((size_t)(it+1), kB, vB);
    compute(kA, vA);
    loadf((size_t)(it+2 < 64 ? it+2 : 0), kA, vA);
    compute(kB, vB);
  }

  // normalize + store: O^T C-layout -> lane owns q = q0+qg*32+c,
  // d = mb*32 + (e&3) + 8*(e>>2) + 4h  (4 consecutive d per e-quad -> b64)
  #pragma unroll
  for(int qg=0; qg<2; qg++){
    lsum[qg] += __shfl_xor(lsum[qg], 32);
    float li = 1.0f / lsum[qg];
    size_t rowoff = (size_t)(b*2048 + q0 + qg*32 + c)*2048 + head*64;
    #pragma unroll
    for(int mb=0; mb<2; mb++){
      #pragma unroll
      for(int g2=0; g2<4; g2++){
        int d0 = mb*32 + 8*g2 + 4*h;
        uint2 wv;
        wv.x = pkh(oacc[qg][mb][4*g2+0]*li, oacc[qg][mb][4*g2+1]*li);
        wv.y = pkh(oacc[qg][mb][4*g2+2]*li, oacc[qg][mb][4*g2+3]*li);
        *(uint2*)&Og[rowoff + d0] = wv;
      }
    }
  }
}

extern "C" void kernel_launch(void* const* d_in, const int* in_sizes, int n_in,
                              void* d_out, int out_size, void* d_ws, size_t ws_size,
                              hipStream_t stream){
  const float* x  = (const float*)d_in[0];
  const float* Wq = (const float*)d_in[1];
  const float* bq = (const float*)d_in[2];
  const float* Wk = (const float*)d_in[3];
  const float* bk = (const float*)d_in[4];
  const float* Wv = (const float*)d_in[5];
  const float* bv = (const float*)d_in[6];
  const float* Wo = (const float*)d_in[7];
  const float* bo = (const float*)d_in[8];

  char* ws = (char*)d_ws;
  short* WT   = (short*)(ws);                 // [3072][2048] f16 (dead after QKV GEMM)
  short* WoT  = (short*)(ws + 25165824);      // [2048][2048] f16
  short* xb   = (short*)(ws + 33554432);      // [4096][2048] f16
  short* QKV  = (short*)(ws + 50331648);      // [4096][3072] f16
  float* bqkv = (float*)(ws + 79691776);      // [3072]
  short* AO   = xb;                           // xb dead after QKV GEMM
  short* Kf   = (short*)(ws);                 // [16][131072] f16 frag-packed K (over dead WT)
  short* Vf   = (short*)(ws + 4194304);       // [16][131072] f16 frag-packed V (over dead WT)

  cast_kernel<<<4096, 256, 0, stream>>>(x, xb, 8388608);
  prep_kernel<<<dim3(32,81), 256, 0, stream>>>(Wq, Wk, Wv, Wo, bq, bk, bv, WT, WoT, bqkv);

  // QKV projection; Q columns pre-scaled by 1/sqrt(64)*log2(e) for exp2 softmax
  gemm_bt_kernel<false><<<dim3(32,24), 256, 0, stream>>>(xb, WT, bqkv, QKV,
                                                         4096, 3072, 2048,
                                                         2048, 0.1803368801111244f);

  fragpack_kernel<<<dim3(32,8,2), 256, 0, stream>>>(QKV, Kf, Vf);

  attn_kernel<<<512, 256, 0, stream>>>(QKV, Kf, Vf, AO, 3072);

  gemm_bt_kernel<true><<<dim3(32,16), 256, 0, stream>>>(AO, WoT, bo, (float*)d_out,
                                                        4096, 2048, 2048, 0, 1.0f);
}

// Round 20
// 304.802 us; speedup vs baseline: 1.0196x; 1.0196x over previous
//
#include <hip/hip_runtime.h>

// GroupedQueryAttention on MI355X (gfx950), round 17 (4th resubmit; rounds
// 16-19 were GPU-broker infra timeouts, kernel never ran).
// B=2, S=2048, E=2048, H=32, KVH=8, G=4, D=64.
// Verified session best on record: round-14 config, 299.7us (round-11 bench).
// This round: attn de-phasing. Round-10 counters (Mfma 40 + VALU 43 ~= 83,
// dur 78 = 31 MFMA + 33 VALU + 14 stall) show the two co-resident waves per
// SIMD run in LOCKSTEP (identical deterministic streams, same start) so the
// MFMA and VALU pipes alternate instead of overlapping (m114 overlap needs
// phase diversity). Fix: merge two q-tiles into one 512-thr block -- waves
// 0-3 = q-tile 2t, waves 4-7 = q-tile 2t+1 (HW: wave w -> SIMD w%4, so each
// SIMD hosts one wave of each half) -- and s_sleep(20) the second half so
// its softmax VALU lands under the first half's QK/PV MFMA. Per-wave body
// byte-identical to round-10 (120 VGPR); launch_bounds(512,2) caps 256.
// GEMM = round-14 verified config (BK=64, (256,2), plain block ids).

typedef __attribute__((ext_vector_type(8)))  short     s16x8;
typedef __attribute__((ext_vector_type(8)))  _Float16  h8;
typedef __attribute__((ext_vector_type(2)))  __fp16    fp16x2;
typedef __attribute__((ext_vector_type(4)))  float     f32x4;
typedef __attribute__((ext_vector_type(16))) float     f32x16;

#define DEVI static __device__ __forceinline__

#if __has_builtin(__builtin_amdgcn_exp2f)
#define EXP2F __builtin_amdgcn_exp2f
#else
#define EXP2F exp2f
#endif

DEVI short f2h(float f){ _Float16 h = (_Float16)f; return __builtin_bit_cast(short, h); }
DEVI unsigned pkh(float a, float b){            // two f32 -> packed f16 (RTZ), 1 instr
  fp16x2 t = __builtin_amdgcn_cvt_pkrtz(a, b);
  return __builtin_bit_cast(unsigned, t);
}

typedef __attribute__((address_space(3))) unsigned       lds_u32;
typedef __attribute__((address_space(1))) const unsigned gbl_u32;
DEVI void glds16(const short* g, short* l){
  __builtin_amdgcn_global_load_lds((gbl_u32*)g, (lds_u32*)l, 16, 0, 0);
}

// ---------------- cast fp32 -> f16 ----------------
__global__ void cast_kernel(const float* __restrict__ in, short* __restrict__ out, int n){
  int i = (blockIdx.x * 256 + threadIdx.x) * 8;
  if(i >= n) return;
  float4 a = *(const float4*)(in + i);
  float4 b = *(const float4*)(in + i + 4);
  s16x8 v;
  v[0]=f2h(a.x); v[1]=f2h(a.y); v[2]=f2h(a.z); v[3]=f2h(a.w);
  v[4]=f2h(b.x); v[5]=f2h(b.y); v[6]=f2h(b.z); v[7]=f2h(b.w);
  *(s16x8*)(out + i) = v;
}

// ---------------- merged weight transposes (fp32 -> f16) + bias concat -------
// grid (32, 81): gy 0..31 Wq, 32..39 Wk, 40..47 Wv, 48..79 Wo, 80 bias concat
__global__ void prep_kernel(const float* __restrict__ Wq, const float* __restrict__ Wk,
                            const float* __restrict__ Wv, const float* __restrict__ Wo,
                            const float* __restrict__ bq, const float* __restrict__ bk,
                            const float* __restrict__ bv,
                            short* __restrict__ WT, short* __restrict__ WoT,
                            float* __restrict__ bqkv){
  __shared__ __align__(16) short tile[64*72];
  const int gy = blockIdx.y;
  const int t = threadIdx.x;
  if(gy >= 80){
    int i = blockIdx.x * 256 + t;
    if(i < 3072) bqkv[i] = (i < 2048) ? bq[i] : (i < 2560 ? bk[i-2048] : bv[i-2560]);
    return;
  }
  const float* src; short* dst; int ldin, by;
  if(gy < 32)      { src = Wq; dst = WT;             ldin = 2048; by = gy;    }
  else if(gy < 40) { src = Wk; dst = WT + 2048*2048; ldin =  512; by = gy-32; }
  else if(gy < 48) { src = Wv; dst = WT + 2560*2048; ldin =  512; by = gy-40; }
  else             { src = Wo; dst = WoT;            ldin = 2048; by = gy-48; }
  const int tr = blockIdx.x * 64;
  const int tc = by * 64;
  for(int c = t; c < 512; c += 256){
    int r = c >> 3, g = c & 7;
    const float* p = src + (size_t)(tr + r) * ldin + tc + g*8;
    s16x8 v;
    #pragma unroll
    for(int e = 0; e < 8; e++) v[e] = f2h(p[e]);
    *(s16x8*)&tile[r*72 + g*8] = v;
  }
  __syncthreads();
  for(int c = t; c < 512; c += 256){
    int r = c >> 3, g = c & 7;
    s16x8 v;
    #pragma unroll
    for(int e = 0; e < 8; e++) v[e] = tile[(g*8+e)*72 + r];
    *(s16x8*)(dst + (size_t)(tc + r) * 2048 + tr + g*8) = v;
  }
}

// ---------------- GEMM (f16): C[M][N] = A[M][K] * BT[N][K]^T + bias[N] -------
// Round-14 verified config: BK=64 (two 32-wide sub-tiles per barrier pair,
// af/bfr regs reused), launch_bounds (256,2), plain block ids.
template<bool OUT_F32>
__global__ __launch_bounds__(256, 2)
void gemm_bt_kernel(const short* __restrict__ A, const short* __restrict__ BT,
                    const float* __restrict__ bias, void* __restrict__ C,
                    int M, int N, int K, int scale_cols, float qscale){
  __shared__ __align__(16) short As[2][128*32];
  __shared__ __align__(16) short Bs[2][128*32];
  const int m0 = blockIdx.x * 128;
  const int n0 = blockIdx.y * 128;
  const int tid = threadIdx.x;
  const int wave = tid >> 6, lane = tid & 63;
  const int l16 = lane & 15, quad = lane >> 4;
  const int wm = (wave >> 1) * 64, wn = (wave & 1) * 64;

  const short* gA = A  + (size_t)(m0 + wave*32 + (lane>>2))*K + (lane&3)*8;
  const short* gB = BT + (size_t)(n0 + wave*32 + (lane>>2))*K + (lane&3)*8;
  short* lA0 = As[0] + wave*1024;
  short* lA1 = As[1] + wave*1024;
  short* lB0 = Bs[0] + wave*1024;
  short* lB1 = Bs[1] + wave*1024;

  f32x4 acc[4][4];
  #pragma unroll
  for(int i=0;i<4;i++)
    #pragma unroll
    for(int j=0;j<4;j++) acc[i][j] = (f32x4)(0.0f);

  for(int k0 = 0; k0 < K; k0 += 64){
    glds16(gA + k0,                     lA0);
    glds16(gA + 16*(size_t)K + k0,      lA0 + 512);
    glds16(gA + k0 + 32,                lA1);
    glds16(gA + 16*(size_t)K + k0 + 32, lA1 + 512);
    glds16(gB + k0,                     lB0);
    glds16(gB + 16*(size_t)K + k0,      lB0 + 512);
    glds16(gB + k0 + 32,                lB1);
    glds16(gB + 16*(size_t)K + k0 + 32, lB1 + 512);
    __syncthreads();
    h8 af[4], bfr[4];
    #pragma unroll
    for(int i=0;i<4;i++){
      af[i]  = *(const h8*)&As[0][(wm + i*16 + l16)*32 + quad*8];
      bfr[i] = *(const h8*)&Bs[0][(wn + i*16 + l16)*32 + quad*8];
    }
    #pragma unroll
    for(int i=0;i<4;i++)
      #pragma unroll
      for(int j=0;j<4;j++)
        acc[i][j] = __builtin_amdgcn_mfma_f32_16x16x32_f16(af[i], bfr[j], acc[i][j], 0, 0, 0);
    #pragma unroll
    for(int i=0;i<4;i++){
      af[i]  = *(const h8*)&As[1][(wm + i*16 + l16)*32 + quad*8];
      bfr[i] = *(const h8*)&Bs[1][(wn + i*16 + l16)*32 + quad*8];
    }
    #pragma unroll
    for(int i=0;i<4;i++)
      #pragma unroll
      for(int j=0;j<4;j++)
        acc[i][j] = __builtin_amdgcn_mfma_f32_16x16x32_f16(af[i], bfr[j], acc[i][j], 0, 0, 0);
    __syncthreads();
  }

  #pragma unroll
  for(int j=0;j<4;j++){
    int col = n0 + wn + j*16 + l16;
    float bb = bias[col];
    float sc = (col < scale_cols) ? qscale : 1.0f;
    #pragma unroll
    for(int i=0;i<4;i++){
      #pragma unroll
      for(int r=0;r<4;r++){
        size_t row = (size_t)(m0 + wm + i*16 + quad*4 + r);
        float v = (acc[i][j][r] + bb) * sc;
        if(OUT_F32) ((float*)C)[row*(size_t)N + col] = v;
        else        ((short*)C)[row*(size_t)N + col] = f2h(v);
      }
    }
  }
}

// ---------------- K/V fragment pre-pack ----------------
// grid (32 tiles, 8 kvh, 2 b), 256 thr. Reads the K and V column slices of
// QKV for one 64-key tile into LDS, emits MFMA A-fragment-ordered chunks:
//   Kf chunk (t,kb,ks2,l):  K[t*64+kb*32+(l&31)][ks2*16+(l>>5)*8 .. +8]
//   Vf chunk (t,kb,ksp,mb,l): keys k0..k0+3, k0+8..k0+11 (k0=kb*32+ksp*16+(l>>5)*4)
//                             at d = mb*32+(l&31)   (the PV kappa order)
// Chunk index within a tile == the lane that will read it -> attn loads are
// lane-contiguous global_load_dwordx4 and the stream is fully sequential.
__global__ void fragpack_kernel(const short* __restrict__ QKV,
                                short* __restrict__ Kf, short* __restrict__ Vf){
  __shared__ __align__(16) short kt[64*72];
  __shared__ __align__(16) short vt[64*72];
  const int t = blockIdx.x, kvh = blockIdx.y, b = blockIdx.z;
  const int tid = threadIdx.x;
  const size_t rowbase = (size_t)(b*2048 + t*64);
  for(int c = tid; c < 512; c += 256){
    int r = c >> 3, g = c & 7;
    const short* src = QKV + (rowbase + r)*3072 + kvh*64 + g*8;
    *(s16x8*)&kt[r*72 + g*8] = *(const s16x8*)(src + 2048);
    *(s16x8*)&vt[r*72 + g*8] = *(const s16x8*)(src + 2560);
  }
  __syncthreads();
  const size_t obase = ((size_t)(b*8 + kvh)*32 + t) * 4096;
  for(int ch = tid; ch < 512; ch += 256){
    int kb = ch >> 8, l = ch & 63;
    int c = l & 31, h = l >> 5;
    // K chunk: ch = kb*256 + ks2*64 + l
    int ks2 = (ch >> 6) & 3;
    *(s16x8*)(Kf + obase + (size_t)ch*8) =
        *(const s16x8*)&kt[(kb*32 + c)*72 + ks2*16 + h*8];
    // V chunk: ch = kb*256 + ksp*128 + mb*64 + l
    int ksp = (ch >> 7) & 1, mb = (ch >> 6) & 1;
    int k0 = kb*32 + ksp*16 + h*4;
    int d  = mb*32 + c;
    s16x8 v;
    #pragma unroll
    for(int j = 0; j < 4; j++){
      v[j]   = vt[(k0 + j)*72 + d];
      v[4+j] = vt[(k0 + 8 + j)*72 + d];
    }
    *(s16x8*)(Vf + obase + (size_t)ch*8) = v;
  }
}

// ---------------- flash attention: LDS-free, de-phased 8-wave blocks -------
// 256 blocks (XCD-swizzled) x 8 waves, 512 thr. Waves 0-3 = q-tile 2*qp,
// waves 4-7 = q-tile 2*qp+1 of the same KV group (wave w -> SIMD w%4, so
// each SIMD hosts one wave of each half). Second half s_sleep(20)s after
// issuing its prefetch so its softmax VALU executes under the first half's
// QK/PV MFMA (anti-phase). Per-wave body identical to round-10: 8 coalesced
// b128 frag loads per 32-key half-tile, S^T = K*Q^T (32x32x16 f16), max-free
// exp2 softmax packed in-register as the PV B-operand, O^T in f32x16,
// register double buffer one half-tile ahead. No LDS, no barriers.
__global__ __launch_bounds__(512, 2)
void attn_kernel(const short* __restrict__ Qg, const short* __restrict__ Kf,
                 const short* __restrict__ Vf, short* __restrict__ Og, int ldq){
  const int L = blockIdx.x;                // 0..255
  const int nid = (L & 7)*32 + (L >> 3);   // XCD swizzle: XCD x owns nid [x*32, x*32+32)
  const int grp = nid >> 4;                // 0..15 = b*8+kvh (2 groups per XCD -> 1 MB L2)
  const int kvh = grp & 7, b = grp >> 3;
  const int tid = threadIdx.x;
  const int wave = tid >> 6, lane = tid & 63;
  const int half = wave >> 2;              // 0: q-tile 2qp, 1: q-tile 2qp+1 (delayed)
  const int w4 = wave & 3;                 // head within group
  const int c = lane & 31, h = lane >> 5;
  const int head = kvh*4 + w4;
  const int qt = (nid & 15)*2 + half;
  const int q0 = qt * 64;

  // Q B-fragments (pre-scaled by 0.125*log2e in GEMM epilogue)
  h8 qreg[4][2];
  #pragma unroll
  for(int ks2=0; ks2<4; ks2++)
    #pragma unroll
    for(int qg=0; qg<2; qg++)
      qreg[ks2][qg] = *(const h8*)(Qg + (size_t)(b*2048 + q0 + qg*32 + c)*ldq
                                      + head*64 + ks2*16 + h*8);

  float lsum[2] = {0.0f, 0.0f};
  f32x16 oacc[2][2];               // [qg][mb]  O^T block: rows d, cols q
  #pragma unroll
  for(int qg=0; qg<2; qg++)
    #pragma unroll
    for(int mb=0; mb<2; mb++) oacc[qg][mb] = (f32x16)(0.0f);

  const short* kp = Kf + (size_t)grp * 131072 + lane*8;
  const short* vp = Vf + (size_t)grp * 131072 + lane*8;

  h8 kA[4], vA[4], kB[4], vB[4];

  auto loadf = [&](size_t it, h8* K, h8* V){
    const short* kq = kp + it*2048;
    const short* vq = vp + it*2048;
    #pragma unroll
    for(int i=0;i<4;i++){
      K[i] = *(const h8*)(kq + i*512);
      V[i] = *(const h8*)(vq + i*512);
    }
  };

  auto compute = [&](const h8* K, const h8* V){
    f32x16 st[2];
    st[0] = (f32x16)(0.0f); st[1] = (f32x16)(0.0f);
    #pragma unroll
    for(int ks2=0; ks2<4; ks2++){
      st[0] = __builtin_amdgcn_mfma_f32_32x32x16_f16(K[ks2], qreg[ks2][0], st[0], 0, 0, 0);
      st[1] = __builtin_amdgcn_mfma_f32_32x32x16_f16(K[ks2], qreg[ks2][1], st[1], 0, 0, 0);
    }
    union H8U { h8 v; unsigned u[4]; };
    H8U pk[2][2];                  // [qg][ksp]
    #pragma unroll
    for(int qg=0; qg<2; qg++){
      float sacc = 0.0f;
      #pragma unroll
      for(int j=0; j<4; j++){
        float pa = EXP2F(st[qg][2*j]);
        float pb = EXP2F(st[qg][2*j+1]);
        sacc += pa + pb;
        pk[qg][0].u[j] = pkh(pa, pb);
      }
      #pragma unroll
      for(int j=0; j<4; j++){
        float pa = EXP2F(st[qg][8+2*j]);
        float pb = EXP2F(st[qg][8+2*j+1]);
        sacc += pa + pb;
        pk[qg][1].u[j] = pkh(pa, pb);
      }
      lsum[qg] += sacc;
    }
    #pragma unroll
    for(int ksp=0; ksp<2; ksp++){
      #pragma unroll
      for(int mb=0; mb<2; mb++){
        oacc[0][mb] = __builtin_amdgcn_mfma_f32_32x32x16_f16(V[ksp*2+mb], pk[0][ksp].v, oacc[0][mb], 0, 0, 0);
        oacc[1][mb] = __builtin_amdgcn_mfma_f32_32x32x16_f16(V[ksp*2+mb], pk[1][ksp].v, oacc[1][mb], 0, 0, 0);
      }
    }
  };

  loadf(0, kA, vA);
  if(half) __builtin_amdgcn_s_sleep(20);   // ~1280 cyc: anti-phase vs half 0
  #pragma unroll 1
  for(int it = 0; it < 64; it += 2){
    loadf((size_t)(it+1), kB, vB);
    compute(kA, vA);
    loadf((size_t)(it+2 < 64 ? it+2 : 0), kA, vA);
    compute(kB, vB);
  }

  // normalize + store: O^T C-layout -> lane owns q = q0+qg*32+c,
  // d = mb*32 + (e&3) + 8*(e>>2) + 4h  (4 consecutive d per e-quad -> b64)
  #pragma unroll
  for(int qg=0; qg<2; qg++){
    lsum[qg] += __shfl_xor(lsum[qg], 32);
    float li = 1.0f / lsum[qg];
    size_t rowoff = (size_t)(b*2048 + q0 + qg*32 + c)*2048 + head*64;
    #pragma unroll
    for(int mb=0; mb<2; mb++){
      #pragma unroll
      for(int g2=0; g2<4; g2++){
        int d0 = mb*32 + 8*g2 + 4*h;
        uint2 wv;
        wv.x = pkh(oacc[qg][mb][4*g2+0]*li, oacc[qg][mb][4*g2+1]*li);
        wv.y = pkh(oacc[qg][mb][4*g2+2]*li, oacc[qg][mb][4*g2+3]*li);
        *(uint2*)&Og[rowoff + d0] = wv;
      }
    }
  }
}

extern "C" void kernel_launch(void* const* d_in, const int* in_sizes, int n_in,
                              void* d_out, int out_size, void* d_ws, size_t ws_size,
                              hipStream_t stream){
  const float* x  = (const float*)d_in[0];
  const float* Wq = (const float*)d_in[1];
  const float* bq = (const float*)d_in[2];
  const float* Wk = (const float*)d_in[3];
  const float* bk = (const float*)d_in[4];
  const float* Wv = (const float*)d_in[5];
  const float* bv = (const float*)d_in[6];
  const float* Wo = (const float*)d_in[7];
  const float* bo = (const float*)d_in[8];

  char* ws = (char*)d_ws;
  short* WT   = (short*)(ws);                 // [3072][2048] f16 (dead after QKV GEMM)
  short* WoT  = (short*)(ws + 25165824);      // [2048][2048] f16
  short* xb   = (short*)(ws + 33554432);      // [4096][2048] f16
  short* QKV  = (short*)(ws + 50331648);      // [4096][3072] f16
  float* bqkv = (float*)(ws + 79691776);      // [3072]
  short* AO   = xb;                           // xb dead after QKV GEMM
  short* Kf   = (short*)(ws);                 // [16][131072] f16 frag-packed K (over dead WT)
  short* Vf   = (short*)(ws + 4194304);       // [16][131072] f16 frag-packed V (over dead WT)

  cast_kernel<<<4096, 256, 0, stream>>>(x, xb, 8388608);
  prep_kernel<<<dim3(32,81), 256, 0, stream>>>(Wq, Wk, Wv, Wo, bq, bk, bv, WT, WoT, bqkv);

  // QKV projection; Q columns pre-scaled by 1/sqrt(64)*log2(e) for exp2 softmax
  gemm_bt_kernel<false><<<dim3(32,24), 256, 0, stream>>>(xb, WT, bqkv, QKV,
                                                         4096, 3072, 2048,
                                                         2048, 0.1803368801111244f);

  fragpack_kernel<<<dim3(32,8,2), 256, 0, stream>>>(QKV, Kf, Vf);

  attn_kernel<<<256, 512, 0, stream>>>(QKV, Kf, Vf, AO, 3072);

  gemm_bt_kernel<true><<<dim3(32,16), 256, 0, stream>>>(AO, WoT, bo, (float*)d_out,
                                                        4096, 2048, 2048, 0, 1.0f);
}